// Round 4
// baseline (342.239 us; speedup 1.0000x reference)
//
#include <hip/hip_runtime.h>

#define N_NODES 50000
#define N_EDGES 800000
#define DIM 128

// ---------------- degree histogram (int) ----------------

__global__ __launch_bounds__(256) void deg_kernel(const int* __restrict__ dst,
                                                  int* __restrict__ degi, int nE) {
    int e = blockIdx.x * 256 + threadIdx.x;
    if (e < nE) atomicAdd(&degi[dst[e]], 1);
}

// ---------------- parallel scan, stage 1: per-1024-chunk inclusive scan ----

__global__ __launch_bounds__(1024) void scan_local(const int* __restrict__ cnt,
                                                   int* __restrict__ rowptr,   // local incl -> rowptr[i+1]
                                                   int* __restrict__ bsum, int n) {
    __shared__ int wsum[16];
    const int t = threadIdx.x;
    const int lane = t & 63;
    const int wid = t >> 6;
    int i = blockIdx.x * 1024 + t;
    int v = (i < n) ? cnt[i] : 0;
    int incl = v;
#pragma unroll
    for (int off = 1; off < 64; off <<= 1) {
        int u = __shfl_up(incl, off, 64);
        if (lane >= off) incl += u;
    }
    if (lane == 63) wsum[wid] = incl;
    __syncthreads();
    if (wid == 0) {
        int wv = (lane < 16) ? wsum[lane] : 0;
#pragma unroll
        for (int off = 1; off < 16; off <<= 1) {
            int u = __shfl_up(wv, off, 64);
            if (lane >= off) wv += u;
        }
        if (lane < 16) wsum[lane] = wv;
    }
    __syncthreads();
    int tot = incl + ((wid > 0) ? wsum[wid - 1] : 0);
    if (i < n) rowptr[i + 1] = tot;            // local inclusive, offset added in apply
    if (t == 1023) bsum[blockIdx.x] = tot;     // chunk total
}

// ---------------- stage 2: apply offsets (each block rescans bsum), cursor, dinv

__global__ __launch_bounds__(256) void scan_apply(const int* __restrict__ cnt,
                                                  int* __restrict__ rowptr,
                                                  int* __restrict__ cursor,
                                                  const int* __restrict__ bsum,
                                                  float* __restrict__ dinv, int n, int nb) {
    __shared__ int excl[64];
    const int t = threadIdx.x;
    if (t < 64) {                               // wave 0: exclusive scan of <=64 partials
        int v = (t < nb) ? bsum[t] : 0;
        int incl = v;
#pragma unroll
        for (int off = 1; off < 64; off <<= 1) {
            int u = __shfl_up(incl, off, 64);
            if (t >= off) incl += u;
        }
        excl[t] = incl - v;
    }
    __syncthreads();
    int i = blockIdx.x * 256 + t;
    if (i == 0) rowptr[0] = 0;
    if (i < n) {
        int incl = rowptr[i + 1] + excl[i >> 10];
        rowptr[i + 1] = incl;
        cursor[i] = incl - cnt[i];
        dinv[i] = rsqrtf((float)cnt[i] + 1.0f);   // +1 self-loop
    }
}

// ---------------- CSR fill (grouped by dst, entries = src) ----------------

__global__ __launch_bounds__(256) void fill_kernel(const int* __restrict__ src,
                                                   const int* __restrict__ dst,
                                                   int* __restrict__ cursor,
                                                   int* __restrict__ csr, int nE) {
    int e = blockIdx.x * 256 + threadIdx.x;
    if (e >= nE) return;
    int d = dst[e];
    int pos = atomicAdd(&cursor[d], 1);
    csr[pos] = src[e];
}

// ---------------- GEMM: O[n,128] = (X[n,128] @ W[128,128]) * dinv[row] -----

__global__ __launch_bounds__(256) void gemm_xw(const float* __restrict__ X,
                                               const float* __restrict__ W,
                                               const float* __restrict__ dinv,
                                               float* __restrict__ O, int nrows) {
    __shared__ float Xs[64][128];
    const int rbase = blockIdx.x * 64;
    const int t = threadIdx.x;

    for (int idx = t; idx < 2048; idx += 256) {
        int r = idx >> 5;
        int gr = rbase + r;
        float4 v = make_float4(0.f, 0.f, 0.f, 0.f);
        if (gr < nrows) v = ((const float4*)X)[(size_t)gr * 32 + (idx & 31)];
        ((float4*)Xs)[idx] = v;
    }
    __syncthreads();

    const int ct = t & 31;        // cols [ct*4, ct*4+4)
    const int rt = t >> 5;        // rows [rt*8, rt*8+8)
    float4 acc[8];
#pragma unroll
    for (int j = 0; j < 8; ++j) acc[j] = make_float4(0.f, 0.f, 0.f, 0.f);

    const float4* W4 = (const float4*)W;
#pragma unroll 4
    for (int k = 0; k < 128; ++k) {
        float4 w = W4[k * 32 + ct];
#pragma unroll
        for (int j = 0; j < 8; ++j) {
            float xv = Xs[rt * 8 + j][k];
            acc[j].x += xv * w.x;
            acc[j].y += xv * w.y;
            acc[j].z += xv * w.z;
            acc[j].w += xv * w.w;
        }
    }

#pragma unroll
    for (int j = 0; j < 8; ++j) {
        int r = rbase + rt * 8 + j;
        if (r < nrows) {
            float di = dinv[r];
            float4 o = make_float4(acc[j].x * di, acc[j].y * di,
                                   acc[j].z * di, acc[j].w * di);
            ((float4*)O)[(size_t)r * 32 + ct] = o;
        }
    }
}

// ---------------- CSR aggregate: out[d] = dinv[d]*(sum hp[s] + hp[d]) + b --
// one wave per node; lane = (half, col): each load instruction gathers
// float4 x 32 cols from TWO edges (1024 B in flight per instr). Main loop
// 16 edges/iter (8 loads = 8 KB outstanding), 8/4/2/1 remainder ladder.

__global__ __launch_bounds__(256) void aggregate_kernel(const float4* __restrict__ H4,
                                                        const int* __restrict__ rowptr,
                                                        const int* __restrict__ csr,
                                                        const float* __restrict__ dinv,
                                                        const float* __restrict__ b,
                                                        float4* __restrict__ out,
                                                        int relu) {
    int node = blockIdx.x * 4 + (threadIdx.x >> 6);
    if (node >= N_NODES) return;
    const int lane = threadIdx.x & 63;
    const int half = lane >> 5;           // which edge of the pair
    const int col  = lane & 31;           // float4 column within the 512B row

    float4 acc = make_float4(0.f, 0.f, 0.f, 0.f);
    if (half == 0) acc = H4[(size_t)node * 32 + col];   // self-loop term

    int j = rowptr[node];
    const int end = rowptr[node + 1];

    for (; j + 16 <= end; j += 16) {
        int s0 = csr[j +  0 + half], s1 = csr[j +  2 + half];
        int s2 = csr[j +  4 + half], s3 = csr[j +  6 + half];
        int s4 = csr[j +  8 + half], s5 = csr[j + 10 + half];
        int s6 = csr[j + 12 + half], s7 = csr[j + 14 + half];
        float4 v0 = H4[(size_t)s0 * 32 + col];
        float4 v1 = H4[(size_t)s1 * 32 + col];
        float4 v2 = H4[(size_t)s2 * 32 + col];
        float4 v3 = H4[(size_t)s3 * 32 + col];
        float4 v4 = H4[(size_t)s4 * 32 + col];
        float4 v5 = H4[(size_t)s5 * 32 + col];
        float4 v6 = H4[(size_t)s6 * 32 + col];
        float4 v7 = H4[(size_t)s7 * 32 + col];
        acc.x += ((v0.x + v1.x) + (v2.x + v3.x)) + ((v4.x + v5.x) + (v6.x + v7.x));
        acc.y += ((v0.y + v1.y) + (v2.y + v3.y)) + ((v4.y + v5.y) + (v6.y + v7.y));
        acc.z += ((v0.z + v1.z) + (v2.z + v3.z)) + ((v4.z + v5.z) + (v6.z + v7.z));
        acc.w += ((v0.w + v1.w) + (v2.w + v3.w)) + ((v4.w + v5.w) + (v6.w + v7.w));
    }
    if (j + 8 <= end) {
        int s0 = csr[j + half], s1 = csr[j + 2 + half];
        int s2 = csr[j + 4 + half], s3 = csr[j + 6 + half];
        float4 v0 = H4[(size_t)s0 * 32 + col];
        float4 v1 = H4[(size_t)s1 * 32 + col];
        float4 v2 = H4[(size_t)s2 * 32 + col];
        float4 v3 = H4[(size_t)s3 * 32 + col];
        acc.x += (v0.x + v1.x) + (v2.x + v3.x);
        acc.y += (v0.y + v1.y) + (v2.y + v3.y);
        acc.z += (v0.z + v1.z) + (v2.z + v3.z);
        acc.w += (v0.w + v1.w) + (v2.w + v3.w);
        j += 8;
    }
    if (j + 4 <= end) {
        int s0 = csr[j + half], s1 = csr[j + 2 + half];
        float4 v0 = H4[(size_t)s0 * 32 + col];
        float4 v1 = H4[(size_t)s1 * 32 + col];
        acc.x += v0.x + v1.x;  acc.y += v0.y + v1.y;
        acc.z += v0.z + v1.z;  acc.w += v0.w + v1.w;
        j += 4;
    }
    if (j + 2 <= end) {
        int s = csr[j + half];
        float4 v = H4[(size_t)s * 32 + col];
        acc.x += v.x; acc.y += v.y; acc.z += v.z; acc.w += v.w;
        j += 2;
    }
    if (j < end && half == 0) {       // odd leftover edge
        int s = csr[j];
        float4 v = H4[(size_t)s * 32 + col];
        acc.x += v.x; acc.y += v.y; acc.z += v.z; acc.w += v.w;
    }

    // combine the two halves
    acc.x += __shfl_xor(acc.x, 32, 64);
    acc.y += __shfl_xor(acc.y, 32, 64);
    acc.z += __shfl_xor(acc.z, 32, 64);
    acc.w += __shfl_xor(acc.w, 32, 64);

    if (half == 0) {
        float di = dinv[node];
        int c = col * 4;
        float4 o;
        o.x = acc.x * di + b[c + 0];
        o.y = acc.y * di + b[c + 1];
        o.z = acc.z * di + b[c + 2];
        o.w = acc.w * di + b[c + 3];
        if (relu) {
            o.x = fmaxf(o.x, 0.f); o.y = fmaxf(o.y, 0.f);
            o.z = fmaxf(o.z, 0.f); o.w = fmaxf(o.w, 0.f);
        }
        out[(size_t)node * 32 + col] = o;
    }
}

// ---------------- launch ----------------

extern "C" void kernel_launch(void* const* d_in, const int* in_sizes, int n_in,
                              void* d_out, int out_size, void* d_ws, size_t ws_size,
                              hipStream_t stream) {
    const float* x  = (const float*)d_in[0];
    const int*   ei = (const int*)d_in[1];
    const float* W1 = (const float*)d_in[2];
    const float* b1 = (const float*)d_in[3];
    const float* W2 = (const float*)d_in[4];
    const float* b2 = (const float*)d_in[5];
    float* out = (float*)d_out;

    const int* src = ei;             // edge_index[0]
    const int* dst = ei + N_EDGES;   // edge_index[1]

    char* p = (char*)d_ws;
    int*   degi   = (int*)p;                 p += ((N_NODES * 4 + 1023) & ~1023);
    float* dinv   = (float*)p;               p += ((N_NODES * 4 + 1023) & ~1023);
    int*   rowptr = (int*)p;                 p += (((N_NODES + 1) * 4 + 1023) & ~1023);
    int*   cursor = (int*)p;                 p += ((N_NODES * 4 + 1023) & ~1023);
    int*   bsum   = (int*)p;                 p += 1024;
    int*   csr    = (int*)p;                 p += ((N_EDGES * 4 + 1023) & ~1023);
    float* bufA   = (float*)p;               p += (size_t)N_NODES * DIM * sizeof(float);
    float* bufB   = (float*)p;

    const int scanBlocks = (N_NODES + 1023) / 1024;   // 49
    const int gemmBlocks = (N_NODES + 63) / 64;       // 782
    const int aggBlocks  = (N_NODES + 3) / 4;         // 12500
    const int nodeBlocks = (N_NODES + 255) / 256;
    const int edgeBlocks = (N_EDGES + 255) / 256;

    // ---- build CSR (grouped by dst) + dinv ----
    hipMemsetAsync(degi, 0, N_NODES * sizeof(int), stream);
    deg_kernel<<<edgeBlocks, 256, 0, stream>>>(dst, degi, N_EDGES);
    scan_local<<<scanBlocks, 1024, 0, stream>>>(degi, rowptr, bsum, N_NODES);
    scan_apply<<<nodeBlocks, 256, 0, stream>>>(degi, rowptr, cursor, bsum, dinv,
                                               N_NODES, scanBlocks);
    fill_kernel<<<edgeBlocks, 256, 0, stream>>>(src, dst, cursor, csr, N_EDGES);

    // ---- layer 1 ----
    gemm_xw<<<gemmBlocks, 256, 0, stream>>>(x, W1, dinv, bufA, N_NODES);
    aggregate_kernel<<<aggBlocks, 256, 0, stream>>>((const float4*)bufA, rowptr, csr,
                                                    dinv, b1, (float4*)bufB, 1);

    // ---- layer 2 ----
    gemm_xw<<<gemmBlocks, 256, 0, stream>>>(bufB, W2, dinv, bufA, N_NODES);
    aggregate_kernel<<<aggBlocks, 256, 0, stream>>>((const float4*)bufA, rowptr, csr,
                                                    dinv, b2, (float4*)out, 0);
}

// Round 5
// 299.775 us; speedup vs baseline: 1.1417x; 1.1417x over previous
//
#include <hip/hip_runtime.h>

#define N_NODES 50000
#define N_EDGES 800000
#define DIM 128

// ---------------- bf16 pack/unpack (RNE) ----------------

__device__ inline unsigned pk_bf16(float a, float b) {
    unsigned ua = __float_as_uint(a); ua = (ua + 0x7FFFu + ((ua >> 16) & 1u)) >> 16;
    unsigned ub = __float_as_uint(b); ub = (ub + 0x7FFFu + ((ub >> 16) & 1u)) >> 16;
    return ua | (ub << 16);
}
__device__ inline float bf_lo(unsigned u) { return __uint_as_float(u << 16); }
__device__ inline float bf_hi(unsigned u) { return __uint_as_float(u & 0xFFFF0000u); }

// ---------------- degree histogram (int) ----------------

__global__ __launch_bounds__(256) void deg_kernel(const int* __restrict__ dst,
                                                  int* __restrict__ degi, int nE) {
    int e = blockIdx.x * 256 + threadIdx.x;
    if (e < nE) atomicAdd(&degi[dst[e]], 1);
}

// ---------------- scan stage 1: per-1024-chunk inclusive scan ----------------

__global__ __launch_bounds__(1024) void scan_local(const int* __restrict__ cnt,
                                                   int* __restrict__ rowptr,
                                                   int* __restrict__ bsum, int n) {
    __shared__ int wsum[16];
    const int t = threadIdx.x;
    const int lane = t & 63;
    const int wid = t >> 6;
    int i = blockIdx.x * 1024 + t;
    int v = (i < n) ? cnt[i] : 0;
    int incl = v;
#pragma unroll
    for (int off = 1; off < 64; off <<= 1) {
        int u = __shfl_up(incl, off, 64);
        if (lane >= off) incl += u;
    }
    if (lane == 63) wsum[wid] = incl;
    __syncthreads();
    if (wid == 0) {
        int wv = (lane < 16) ? wsum[lane] : 0;
#pragma unroll
        for (int off = 1; off < 16; off <<= 1) {
            int u = __shfl_up(wv, off, 64);
            if (lane >= off) wv += u;
        }
        if (lane < 16) wsum[lane] = wv;
    }
    __syncthreads();
    int tot = incl + ((wid > 0) ? wsum[wid - 1] : 0);
    if (i < n) rowptr[i + 1] = tot;
    if (t == 1023) bsum[blockIdx.x] = tot;
}

// ---------------- scan stage 2: apply offsets, cursor, dinv ----------------

__global__ __launch_bounds__(256) void scan_apply(const int* __restrict__ cnt,
                                                  int* __restrict__ rowptr,
                                                  int* __restrict__ cursor,
                                                  const int* __restrict__ bsum,
                                                  float* __restrict__ dinv, int n, int nb) {
    __shared__ int excl[64];
    const int t = threadIdx.x;
    if (t < 64) {
        int v = (t < nb) ? bsum[t] : 0;
        int incl = v;
#pragma unroll
        for (int off = 1; off < 64; off <<= 1) {
            int u = __shfl_up(incl, off, 64);
            if (t >= off) incl += u;
        }
        excl[t] = incl - v;
    }
    __syncthreads();
    int i = blockIdx.x * 256 + t;
    if (i == 0) rowptr[0] = 0;
    if (i < n) {
        int incl = rowptr[i + 1] + excl[i >> 10];
        rowptr[i + 1] = incl;
        cursor[i] = incl - cnt[i];
        dinv[i] = rsqrtf((float)cnt[i] + 1.0f);   // +1 self-loop
    }
}

// ---------------- CSR fill (grouped by dst, entries = src) ----------------

__global__ __launch_bounds__(256) void fill_kernel(const int* __restrict__ src,
                                                   const int* __restrict__ dst,
                                                   int* __restrict__ cursor,
                                                   int* __restrict__ csr, int nE) {
    int e = blockIdx.x * 256 + threadIdx.x;
    if (e >= nE) return;
    int d = dst[e];
    int pos = atomicAdd(&cursor[d], 1);
    csr[pos] = src[e];
}

// ---------------- GEMM: hp[n,128](bf16) = (X[n,128] @ W[128,128]) * dinv ----
// 64 rows/block, thread = 8 rows x 4 cols; LDS k-blocked x4 (ds_read_b128).

__global__ __launch_bounds__(256) void gemm_xw(const float* __restrict__ X,
                                               const float* __restrict__ W,
                                               const float* __restrict__ dinv,
                                               uint2* __restrict__ O,     // bf16x4 per uint2
                                               int nrows) {
    __shared__ float Xs[64][128];
    const int rbase = blockIdx.x * 64;
    const int t = threadIdx.x;

    for (int idx = t; idx < 2048; idx += 256) {
        int r = idx >> 5;
        int gr = rbase + r;
        float4 v = make_float4(0.f, 0.f, 0.f, 0.f);
        if (gr < nrows) v = ((const float4*)X)[(size_t)gr * 32 + (idx & 31)];
        ((float4*)Xs)[idx] = v;
    }
    __syncthreads();

    const int ct = t & 31;        // cols [ct*4, ct*4+4)
    const int rt = t >> 5;        // rows [rt*8, rt*8+8)
    float4 acc[8];
#pragma unroll
    for (int j = 0; j < 8; ++j) acc[j] = make_float4(0.f, 0.f, 0.f, 0.f);

    const float4* W4 = (const float4*)W;
    for (int k0 = 0; k0 < 128; k0 += 4) {
        float4 xk[8];
#pragma unroll
        for (int j = 0; j < 8; ++j)
            xk[j] = *(const float4*)&Xs[rt * 8 + j][k0];   // b128, 2-addr broadcast
#pragma unroll
        for (int kk = 0; kk < 4; ++kk) {
            float4 w = W4[(k0 + kk) * 32 + ct];
#pragma unroll
            for (int j = 0; j < 8; ++j) {
                float xv = (kk == 0) ? xk[j].x : (kk == 1) ? xk[j].y
                          : (kk == 2) ? xk[j].z : xk[j].w;
                acc[j].x += xv * w.x;
                acc[j].y += xv * w.y;
                acc[j].z += xv * w.z;
                acc[j].w += xv * w.w;
            }
        }
    }

#pragma unroll
    for (int j = 0; j < 8; ++j) {
        int r = rbase + rt * 8 + j;
        if (r < nrows) {
            float di = dinv[r];
            uint2 o;
            o.x = pk_bf16(acc[j].x * di, acc[j].y * di);
            o.y = pk_bf16(acc[j].z * di, acc[j].w * di);
            O[(size_t)r * 32 + ct] = o;
        }
    }
}

// ---------------- CSR aggregate (bf16 gather): ---------------------------
// out[d] = dinv[d]*(sum hp[s] + hp[d]) + b.  One wave per node; lane =
// (half, col): each uint2 load gathers 4 bf16 x 32 cols from TWO edges
// (512 B per instr). 16 edges/iter main loop, 8/4/2/1 remainder ladder.

__global__ __launch_bounds__(256) void aggregate_kernel(const uint2* __restrict__ H2,
                                                        const int* __restrict__ rowptr,
                                                        const int* __restrict__ csr,
                                                        const float* __restrict__ dinv,
                                                        const float4* __restrict__ b4,
                                                        float4* __restrict__ out,
                                                        int relu) {
    int node = blockIdx.x * 4 + (threadIdx.x >> 6);
    if (node >= N_NODES) return;
    const int lane = threadIdx.x & 63;
    const int half = lane >> 5;           // which edge of the pair
    const int col  = lane & 31;           // uint2 column (4 channels)

    float4 acc = make_float4(0.f, 0.f, 0.f, 0.f);
    if (half == 0) {                      // self-loop term
        uint2 v = H2[(size_t)node * 32 + col];
        acc.x = bf_lo(v.x); acc.y = bf_hi(v.x);
        acc.z = bf_lo(v.y); acc.w = bf_hi(v.y);
    }

    int j = rowptr[node];
    const int end = rowptr[node + 1];

#define ACCUM(v) do { \
        acc.x += bf_lo((v).x); acc.y += bf_hi((v).x); \
        acc.z += bf_lo((v).y); acc.w += bf_hi((v).y); } while (0)

    for (; j + 16 <= end; j += 16) {
        int s0 = csr[j +  0 + half], s1 = csr[j +  2 + half];
        int s2 = csr[j +  4 + half], s3 = csr[j +  6 + half];
        int s4 = csr[j +  8 + half], s5 = csr[j + 10 + half];
        int s6 = csr[j + 12 + half], s7 = csr[j + 14 + half];
        uint2 v0 = H2[(size_t)s0 * 32 + col];
        uint2 v1 = H2[(size_t)s1 * 32 + col];
        uint2 v2 = H2[(size_t)s2 * 32 + col];
        uint2 v3 = H2[(size_t)s3 * 32 + col];
        uint2 v4 = H2[(size_t)s4 * 32 + col];
        uint2 v5 = H2[(size_t)s5 * 32 + col];
        uint2 v6 = H2[(size_t)s6 * 32 + col];
        uint2 v7 = H2[(size_t)s7 * 32 + col];
        ACCUM(v0); ACCUM(v1); ACCUM(v2); ACCUM(v3);
        ACCUM(v4); ACCUM(v5); ACCUM(v6); ACCUM(v7);
    }
    if (j + 8 <= end) {
        int s0 = csr[j + half], s1 = csr[j + 2 + half];
        int s2 = csr[j + 4 + half], s3 = csr[j + 6 + half];
        uint2 v0 = H2[(size_t)s0 * 32 + col];
        uint2 v1 = H2[(size_t)s1 * 32 + col];
        uint2 v2 = H2[(size_t)s2 * 32 + col];
        uint2 v3 = H2[(size_t)s3 * 32 + col];
        ACCUM(v0); ACCUM(v1); ACCUM(v2); ACCUM(v3);
        j += 8;
    }
    if (j + 4 <= end) {
        int s0 = csr[j + half], s1 = csr[j + 2 + half];
        uint2 v0 = H2[(size_t)s0 * 32 + col];
        uint2 v1 = H2[(size_t)s1 * 32 + col];
        ACCUM(v0); ACCUM(v1);
        j += 4;
    }
    if (j + 2 <= end) {
        int s = csr[j + half];
        uint2 v = H2[(size_t)s * 32 + col];
        ACCUM(v);
        j += 2;
    }
    if (j < end && half == 0) {
        int s = csr[j];
        uint2 v = H2[(size_t)s * 32 + col];
        ACCUM(v);
    }
#undef ACCUM

    acc.x += __shfl_xor(acc.x, 32, 64);
    acc.y += __shfl_xor(acc.y, 32, 64);
    acc.z += __shfl_xor(acc.z, 32, 64);
    acc.w += __shfl_xor(acc.w, 32, 64);

    if (half == 0) {
        float di = dinv[node];
        float4 bb = b4[col];
        float4 o;
        o.x = acc.x * di + bb.x;
        o.y = acc.y * di + bb.y;
        o.z = acc.z * di + bb.z;
        o.w = acc.w * di + bb.w;
        if (relu) {
            o.x = fmaxf(o.x, 0.f); o.y = fmaxf(o.y, 0.f);
            o.z = fmaxf(o.z, 0.f); o.w = fmaxf(o.w, 0.f);
        }
        out[(size_t)node * 32 + col] = o;
    }
}

// ---------------- launch ----------------

extern "C" void kernel_launch(void* const* d_in, const int* in_sizes, int n_in,
                              void* d_out, int out_size, void* d_ws, size_t ws_size,
                              hipStream_t stream) {
    const float* x  = (const float*)d_in[0];
    const int*   ei = (const int*)d_in[1];
    const float* W1 = (const float*)d_in[2];
    const float* b1 = (const float*)d_in[3];
    const float* W2 = (const float*)d_in[4];
    const float* b2 = (const float*)d_in[5];
    float* out = (float*)d_out;

    const int* src = ei;             // edge_index[0]
    const int* dst = ei + N_EDGES;   // edge_index[1]

    char* p = (char*)d_ws;
    int*   degi   = (int*)p;                 p += ((N_NODES * 4 + 1023) & ~1023);
    float* dinv   = (float*)p;               p += ((N_NODES * 4 + 1023) & ~1023);
    int*   rowptr = (int*)p;                 p += (((N_NODES + 1) * 4 + 1023) & ~1023);
    int*   cursor = (int*)p;                 p += ((N_NODES * 4 + 1023) & ~1023);
    int*   bsum   = (int*)p;                 p += 1024;
    int*   csr    = (int*)p;                 p += ((N_EDGES * 4 + 1023) & ~1023);
    uint2* hpB    = (uint2*)p;               p += (size_t)N_NODES * DIM * 2;   // bf16 table
    float* bufB   = (float*)p;                                                  // fp32 h1

    const int scanBlocks = (N_NODES + 1023) / 1024;   // 49
    const int gemmBlocks = (N_NODES + 63) / 64;       // 782
    const int aggBlocks  = (N_NODES + 3) / 4;         // 12500
    const int nodeBlocks = (N_NODES + 255) / 256;
    const int edgeBlocks = (N_EDGES + 255) / 256;

    // ---- build CSR (grouped by dst) + dinv ----
    hipMemsetAsync(degi, 0, N_NODES * sizeof(int), stream);
    deg_kernel<<<edgeBlocks, 256, 0, stream>>>(dst, degi, N_EDGES);
    scan_local<<<scanBlocks, 1024, 0, stream>>>(degi, rowptr, bsum, N_NODES);
    scan_apply<<<nodeBlocks, 256, 0, stream>>>(degi, rowptr, cursor, bsum, dinv,
                                               N_NODES, scanBlocks);
    fill_kernel<<<edgeBlocks, 256, 0, stream>>>(src, dst, cursor, csr, N_EDGES);

    // ---- layer 1: hp1(bf16) = (x@W1)*dinv ; aggregate+bias+relu -> bufB(fp32) ----
    gemm_xw<<<gemmBlocks, 256, 0, stream>>>(x, W1, dinv, hpB, N_NODES);
    aggregate_kernel<<<aggBlocks, 256, 0, stream>>>(hpB, rowptr, csr, dinv,
                                                    (const float4*)b1, (float4*)bufB, 1);

    // ---- layer 2: hp2(bf16) = (h1@W2)*dinv ; aggregate+bias -> out ----
    gemm_xw<<<gemmBlocks, 256, 0, stream>>>(bufB, W2, dinv, hpB, N_NODES);
    aggregate_kernel<<<aggBlocks, 256, 0, stream>>>(hpB, rowptr, csr, dinv,
                                                    (const float4*)b2, (float4*)out, 0);
}